// Round 1
// baseline (388.133 us; speedup 1.0000x reference)
//
#include <hip/hip_runtime.h>
#include <math.h>

#define BB 32
#define TT 8192
#define CCH 128
#define OO 64
#define DD 288
#define NFREQ 12
#define NIJ 144

// ---------------- K0: transpose heads [64][288] -> Ht [288][64] ----------------
__global__ __launch_bounds__(256) void k0_transpose_heads(const float* __restrict__ heads,
                                                          float* __restrict__ Ht) {
    int idx = blockIdx.x * 256 + threadIdx.x;
    if (idx < OO * DD) {
        int o = idx / DD;
        int d = idx - o * DD;
        Ht[d * OO + o] = heads[idx];
    }
}

// ---------------- K1: fourier emb + scores + softmax -> w [B][O][C] ----------------
#define IJ_CHUNK 36
#define EMB_LD 129   // padded row (bank-conflict-free)

__global__ __launch_bounds__(256) void k1_weights(const float* __restrict__ pos,
                                                  const float* __restrict__ Ht,
                                                  float* __restrict__ w) {
    __shared__ float smem[2 * IJ_CHUNK * EMB_LD];   // 9288 floats = 37 KB
    float* cos_s = smem;
    float* sin_s = smem + IJ_CHUNK * EMB_LD;

    const int b = blockIdx.x;
    const int tid = threadIdx.x;
    const int c = tid & 127;
    // h is uniform within each wave (64 | 128); force scalar so heads reads s_load
    const int h = __builtin_amdgcn_readfirstlane(tid >> 7);

    const float* posb = pos + b * CCH * 2;
    const float S = 4.487989505128276f;  // 2*pi/1.4

    float accs[32];
#pragma unroll
    for (int k = 0; k < 32; ++k) accs[k] = 0.f;

#pragma unroll 1
    for (int cc = 0; cc < NIJ; cc += IJ_CHUNK) {
        // compute cos/sin for ij in [cc, cc+36) for all 128 channels
#pragma unroll 1
        for (int it = 0; it < (IJ_CHUNK * CCH) / 256; ++it) {
            int idx = it * 256 + tid;
            int ec = idx & 127;
            int ijl = idx >> 7;
            int ij = cc + ijl;
            int i = ij / NFREQ;
            int j = ij - i * NFREQ;
            float px = posb[2 * ec] + 0.2f;
            float py = posb[2 * ec + 1] + 0.2f;
            float ang = px * (S * (float)i) + py * (S * (float)j);
            float sv, cv;
            sincosf(ang, &sv, &cv);
            cos_s[ijl * EMB_LD + ec] = cv;
            sin_s[ijl * EMB_LD + ec] = sv;
        }
        __syncthreads();
        // accumulate scores: this thread owns channel c, o-range [h*32, h*32+32)
#pragma unroll 4
        for (int ijl = 0; ijl < IJ_CHUNK; ++ijl) {
            float cv = cos_s[ijl * EMB_LD + c];
            float sv = sin_s[ijl * EMB_LD + c];
            const float* hc = Ht + (cc + ijl) * OO + h * 32;
            const float* hs = Ht + (NIJ + cc + ijl) * OO + h * 32;
#pragma unroll
            for (int k = 0; k < 32; ++k) {
                accs[k] = fmaf(cv, hc[k], accs[k]);
                accs[k] = fmaf(sv, hs[k], accs[k]);
            }
        }
        __syncthreads();
    }

    // scores -> LDS [64][129]
    float* sc = smem;
#pragma unroll
    for (int k = 0; k < 32; ++k) {
        sc[(h * 32 + k) * EMB_LD + c] = accs[k];
    }
    __syncthreads();

    // softmax over channels per o-row; write weights
    if (tid < OO) {
        int o = tid;
        float m = -1e30f;
        for (int c2 = 0; c2 < CCH; ++c2) m = fmaxf(m, sc[o * EMB_LD + c2]);
        float s = 0.f;
        for (int c2 = 0; c2 < CCH; ++c2) {
            float e = expf(sc[o * EMB_LD + c2] - m);
            sc[o * EMB_LD + c2] = e;
            s += e;
        }
        float inv = 1.f / s;
        float* wrow = w + (b * OO + o) * CCH;
        for (int c2 = 0; c2 < CCH; ++c2) wrow[c2] = sc[o * EMB_LD + c2] * inv;
    }
}

// ---------------- K2: out[b,t,o] = sum_c eeg[b,t,c] * w[b,o,c] ----------------
// 1 wave per block; lane = t; 64 fp32 accumulators; w via uniform scalar loads.
#define TBL 64
#define TILE_LD 17   // padded row

__global__ __launch_bounds__(64) void k2_merge(const float* __restrict__ eeg,
                                               const float* __restrict__ w,
                                               float* __restrict__ out) {
    __shared__ float tile[TBL * TILE_LD];  // 4.4 KB
    const int b = blockIdx.y;
    const int t0 = blockIdx.x * TBL;
    const int tid = threadIdx.x;

    const float* eb = eeg + ((size_t)b * TT + t0) * CCH;
    const float* wb = w + b * OO * CCH;

    float acc[OO];
#pragma unroll
    for (int o = 0; o < OO; ++o) acc[o] = 0.f;

#pragma unroll 1
    for (int ct = 0; ct < CCH; ct += 16) {
        // cooperative coalesced load of [64 t][16 c] into LDS
#pragma unroll
        for (int pass = 0; pass < 16; ++pass) {
            int idx = pass * 64 + tid;
            int r = idx >> 4;
            int c4 = idx & 15;
            tile[r * TILE_LD + c4] = eb[r * CCH + ct + c4];
        }
        __syncthreads();
        float e[16];
#pragma unroll
        for (int k = 0; k < 16; ++k) e[k] = tile[tid * TILE_LD + k];
#pragma unroll
        for (int o = 0; o < OO; ++o) {
            float a = acc[o];
#pragma unroll
            for (int k = 0; k < 16; ++k) a = fmaf(e[k], wb[o * CCH + ct + k], a);
            acc[o] = a;
        }
        __syncthreads();
    }

    // store via LDS transpose in o-chunks of 16 (coalesced 64B segments)
#pragma unroll 1
    for (int oc = 0; oc < OO; oc += 16) {
#pragma unroll
        for (int k = 0; k < 16; ++k) tile[tid * TILE_LD + k] = acc[oc + k];
        __syncthreads();
#pragma unroll
        for (int pass = 0; pass < 16; ++pass) {
            int idx = pass * 64 + tid;
            int r = idx >> 4;
            int c4 = idx & 15;
            out[((size_t)b * TT + t0 + r) * OO + oc + c4] = tile[r * TILE_LD + c4];
        }
        __syncthreads();
    }
}

extern "C" void kernel_launch(void* const* d_in, const int* in_sizes, int n_in,
                              void* d_out, int out_size, void* d_ws, size_t ws_size,
                              hipStream_t stream) {
    const float* eeg   = (const float*)d_in[0];   // [B,T,C]
    const float* pos   = (const float*)d_in[1];   // [B,C,2]
    const float* heads = (const float*)d_in[2];   // [O,D]
    float* out = (float*)d_out;                   // [B,T,O]

    float* ws_f = (float*)d_ws;
    float* Ht = ws_f;                 // 288*64 = 18432 floats
    float* w  = ws_f + DD * OO;       // 32*64*128 = 262144 floats

    k0_transpose_heads<<<(OO * DD + 255) / 256, 256, 0, stream>>>(heads, Ht);
    k1_weights<<<BB, 256, 0, stream>>>(pos, Ht, w);
    k2_merge<<<dim3(TT / TBL, BB), 64, 0, stream>>>(eeg, w, out);
}

// Round 2
// 301.590 us; speedup vs baseline: 1.2870x; 1.2870x over previous
//
#include <hip/hip_runtime.h>
#include <math.h>

#define BB 32
#define TT 8192
#define CCH 128
#define OO 64
#define DD 288
#define NFREQ 12
#define NIJ 144

// ---------------- K0: transpose heads [64][288] -> Ht [288][64] ----------------
__global__ __launch_bounds__(256) void k0_transpose_heads(const float* __restrict__ heads,
                                                          float* __restrict__ Ht) {
    int idx = blockIdx.x * 256 + threadIdx.x;
    if (idx < OO * DD) {
        int o = idx / DD;
        int d = idx - o * DD;
        Ht[d * OO + o] = heads[idx];
    }
}

// ---------------- K1: fourier emb + scores + softmax -> w [B][O][C] ----------------
// grid (32 b, 4 o-groups of 16); 256 threads. Each thread: channel c = tid&127,
// o-subrange of 8 (hh = tid>>7). Parallel softmax tail (16 threads per o-row).
#define IJ_CHUNK 36
#define EMB_LD 129

__global__ __launch_bounds__(256) void k1_weights(const float* __restrict__ pos,
                                                  const float* __restrict__ Ht,
                                                  float* __restrict__ w) {
    __shared__ float smem[2 * IJ_CHUNK * EMB_LD];   // 9288 floats = 37 KB
    float* cos_s = smem;
    float* sin_s = smem + IJ_CHUNK * EMB_LD;

    const int b = blockIdx.x;
    const int obase = blockIdx.y * 16;
    const int tid = threadIdx.x;
    const int c = tid & 127;
    const int hh = __builtin_amdgcn_readfirstlane(tid >> 7);  // wave-uniform

    const float* posb = pos + b * CCH * 2;
    const float S = 4.487989505128276f;  // 2*pi/1.4

    float accs[8];
#pragma unroll
    for (int k = 0; k < 8; ++k) accs[k] = 0.f;

#pragma unroll 1
    for (int cc = 0; cc < NIJ; cc += IJ_CHUNK) {
#pragma unroll 1
        for (int it = 0; it < (IJ_CHUNK * CCH) / 256; ++it) {
            int idx = it * 256 + tid;
            int ec = idx & 127;
            int ijl = idx >> 7;
            int ij = cc + ijl;
            int i = ij / NFREQ;
            int j = ij - i * NFREQ;
            float px = posb[2 * ec] + 0.2f;
            float py = posb[2 * ec + 1] + 0.2f;
            float ang = px * (S * (float)i) + py * (S * (float)j);
            float sv, cv;
            __sincosf(ang, &sv, &cv);
            cos_s[ijl * EMB_LD + ec] = cv;
            sin_s[ijl * EMB_LD + ec] = sv;
        }
        __syncthreads();
#pragma unroll 4
        for (int ijl = 0; ijl < IJ_CHUNK; ++ijl) {
            float cv = cos_s[ijl * EMB_LD + c];
            float sv = sin_s[ijl * EMB_LD + c];
            const float* hc = Ht + (cc + ijl) * OO + obase + hh * 8;
            const float* hs = Ht + (NIJ + cc + ijl) * OO + obase + hh * 8;
#pragma unroll
            for (int k = 0; k < 8; ++k) {
                accs[k] = fmaf(cv, hc[k], fmaf(sv, hs[k], accs[k]));
            }
        }
        __syncthreads();
    }

    // scores -> LDS [16][129]
    float* sc = smem;
#pragma unroll
    for (int k = 0; k < 8; ++k) {
        sc[(hh * 8 + k) * EMB_LD + c] = accs[k];
    }
    __syncthreads();

    // parallel softmax: o16 = tid>>4 owns one o-row; part = tid&15 owns 8 channels
    float* red  = smem + 16 * EMB_LD;        // 256 floats
    float* red2 = red + 256;                 // 256 floats
    const int o16 = tid >> 4;
    const int part = tid & 15;
    const float* srow = sc + o16 * EMB_LD + part * 8;

    float m = -1e30f;
#pragma unroll
    for (int j = 0; j < 8; ++j) m = fmaxf(m, srow[j]);
    red[o16 * 16 + part] = m;
    __syncthreads();
    float M = red[o16 * 16];
#pragma unroll
    for (int p = 1; p < 16; ++p) M = fmaxf(M, red[o16 * 16 + p]);

    float ev[8];
    float s = 0.f;
#pragma unroll
    for (int j = 0; j < 8; ++j) { ev[j] = __expf(srow[j] - M); s += ev[j]; }
    red2[o16 * 16 + part] = s;
    __syncthreads();
    float Sum = 0.f;
#pragma unroll
    for (int p = 0; p < 16; ++p) Sum += red2[o16 * 16 + p];
    float inv = 1.f / Sum;

    float* wrow = w + ((size_t)(b * OO + obase + o16)) * CCH + part * 8;
#pragma unroll
    for (int j = 0; j < 8; ++j) wrow[j] = ev[j] * inv;
}

// ---------------- K2: out[b,t,o] = sum_c eeg[b,t,c] * w[b,o,c] ----------------
// 256 threads = 4 independent waves (no __syncthreads). Each wave owns 64 t-rows,
// lane owns one row, acc[64]. eeg staged per-wave via coalesced float4 (full
// 128B lines). Weights wave-uniform -> s_load + v_fmac. Output transposed
// per-wave through LDS [64][33] and stored as full 128B lines per instruction.
#define K2_LD 36   // staging row stride (floats); conflict-free for both patterns

__global__ __launch_bounds__(256, 4) void k2_merge(const float* __restrict__ eeg,
                                                   const float* __restrict__ w,
                                                   float* __restrict__ out) {
    __shared__ float lds[4 * 64 * K2_LD];   // 36 KB
    const int b = blockIdx.y;
    const int t0 = blockIdx.x * 256;
    const int lane = threadIdx.x & 63;
    const int wv = __builtin_amdgcn_readfirstlane(threadIdx.x >> 6);
    float* lw = lds + wv * 64 * K2_LD;

    const float* eb = eeg + ((size_t)b * TT + t0 + wv * 64) * CCH;
    const float* wb = w + (size_t)b * OO * CCH;   // uniform -> scalar loads

    float acc[OO];
#pragma unroll
    for (int o = 0; o < OO; ++o) acc[o] = 0.f;

#pragma unroll 1
    for (int ct = 0; ct < CCH; ct += 32) {
        // stage this wave's 64 rows x 32 cols: 8 float4 per lane, coalesced
#pragma unroll
        for (int p = 0; p < 8; ++p) {
            int idx = p * 64 + lane;
            int r = idx >> 3;
            int c4 = idx & 7;
            float4 v = *(const float4*)(eb + r * CCH + ct + c4 * 4);
            *(float4*)(lw + r * K2_LD + c4 * 4) = v;
        }
        __builtin_amdgcn_wave_barrier();
        // accumulate: k in chunks of 8 to bound register pressure
#pragma unroll 1
        for (int k8 = 0; k8 < 4; ++k8) {
            float4 va = *(const float4*)(lw + lane * K2_LD + k8 * 8);
            float4 vb = *(const float4*)(lw + lane * K2_LD + k8 * 8 + 4);
#pragma unroll
            for (int o = 0; o < OO; ++o) {
                const float* wr = wb + o * CCH + ct + k8 * 8;
                float a = acc[o];
                a = fmaf(va.x, wr[0], a);
                a = fmaf(va.y, wr[1], a);
                a = fmaf(va.z, wr[2], a);
                a = fmaf(va.w, wr[3], a);
                a = fmaf(vb.x, wr[4], a);
                a = fmaf(vb.y, wr[5], a);
                a = fmaf(vb.z, wr[6], a);
                a = fmaf(vb.w, wr[7], a);
                acc[o] = a;
            }
        }
        __builtin_amdgcn_wave_barrier();
    }

    // output: per-wave transpose in o-halves via LDS [64][33] (flat view of region)
#pragma unroll 1
    for (int oh = 0; oh < 2; ++oh) {
#pragma unroll
        for (int j = 0; j < 32; ++j) lw[lane * 33 + j] = acc[oh * 32 + j];
        __builtin_amdgcn_wave_barrier();
#pragma unroll
        for (int p = 0; p < 8; ++p) {
            int idx = p * 64 + lane;
            int r = idx >> 3;
            int f4 = idx & 7;
            float4 v;
            v.x = lw[r * 33 + f4 * 4 + 0];
            v.y = lw[r * 33 + f4 * 4 + 1];
            v.z = lw[r * 33 + f4 * 4 + 2];
            v.w = lw[r * 33 + f4 * 4 + 3];
            *(float4*)(out + ((size_t)b * TT + t0 + wv * 64 + r) * OO + oh * 32 + f4 * 4) = v;
        }
        __builtin_amdgcn_wave_barrier();
    }
}

extern "C" void kernel_launch(void* const* d_in, const int* in_sizes, int n_in,
                              void* d_out, int out_size, void* d_ws, size_t ws_size,
                              hipStream_t stream) {
    const float* eeg   = (const float*)d_in[0];   // [B,T,C]
    const float* pos   = (const float*)d_in[1];   // [B,C,2]
    const float* heads = (const float*)d_in[2];   // [O,D]
    float* out = (float*)d_out;                   // [B,T,O]

    float* ws_f = (float*)d_ws;
    float* Ht = ws_f;                 // 288*64 = 18432 floats
    float* w  = ws_f + DD * OO;       // 32*64*128 = 262144 floats

    k0_transpose_heads<<<(OO * DD + 255) / 256, 256, 0, stream>>>(heads, Ht);
    k1_weights<<<dim3(BB, 4), 256, 0, stream>>>(pos, Ht, w);
    k2_merge<<<dim3(TT / 256, BB), 256, 0, stream>>>(eeg, w, out);
}

// Round 3
// 161.323 us; speedup vs baseline: 2.4059x; 1.8695x over previous
//
#include <hip/hip_runtime.h>
#include <math.h>

#define BB 32
#define TT 8192
#define CCH 128
#define OO 64
#define DD 288
#define NFREQ 12
#define NIJ 144

// ---------------- K0: transpose heads [64][288] -> Ht [288][64] ----------------
__global__ __launch_bounds__(256) void k0_transpose_heads(const float* __restrict__ heads,
                                                          float* __restrict__ Ht) {
    int idx = blockIdx.x * 256 + threadIdx.x;
    if (idx < OO * DD) {
        int o = idx / DD;
        int d = idx - o * DD;
        Ht[d * OO + o] = heads[idx];
    }
}

// ---------------- K1: fourier emb + scores + softmax -> w [B][O][C] ----------------
#define IJ_CHUNK 36
#define EMB_LD 129

__global__ __launch_bounds__(256) void k1_weights(const float* __restrict__ pos,
                                                  const float* __restrict__ Ht,
                                                  float* __restrict__ w) {
    __shared__ float smem[2 * IJ_CHUNK * EMB_LD];   // 9288 floats = 37 KB
    float* cos_s = smem;
    float* sin_s = smem + IJ_CHUNK * EMB_LD;

    const int b = blockIdx.x;
    const int obase = blockIdx.y * 16;
    const int tid = threadIdx.x;
    const int c = tid & 127;
    const int hh = __builtin_amdgcn_readfirstlane(tid >> 7);  // wave-uniform

    const float* posb = pos + b * CCH * 2;
    const float S = 4.487989505128276f;  // 2*pi/1.4

    float accs[8];
#pragma unroll
    for (int k = 0; k < 8; ++k) accs[k] = 0.f;

#pragma unroll 1
    for (int cc = 0; cc < NIJ; cc += IJ_CHUNK) {
#pragma unroll 1
        for (int it = 0; it < (IJ_CHUNK * CCH) / 256; ++it) {
            int idx = it * 256 + tid;
            int ec = idx & 127;
            int ijl = idx >> 7;
            int ij = cc + ijl;
            int i = ij / NFREQ;
            int j = ij - i * NFREQ;
            float px = posb[2 * ec] + 0.2f;
            float py = posb[2 * ec + 1] + 0.2f;
            float ang = px * (S * (float)i) + py * (S * (float)j);
            float sv, cv;
            __sincosf(ang, &sv, &cv);
            cos_s[ijl * EMB_LD + ec] = cv;
            sin_s[ijl * EMB_LD + ec] = sv;
        }
        __syncthreads();
#pragma unroll 4
        for (int ijl = 0; ijl < IJ_CHUNK; ++ijl) {
            float cv = cos_s[ijl * EMB_LD + c];
            float sv = sin_s[ijl * EMB_LD + c];
            const float* hc = Ht + (cc + ijl) * OO + obase + hh * 8;
            const float* hs = Ht + (NIJ + cc + ijl) * OO + obase + hh * 8;
#pragma unroll
            for (int k = 0; k < 8; ++k) {
                accs[k] = fmaf(cv, hc[k], fmaf(sv, hs[k], accs[k]));
            }
        }
        __syncthreads();
    }

    // scores -> LDS [16][129]
    float* sc = smem;
#pragma unroll
    for (int k = 0; k < 8; ++k) {
        sc[(hh * 8 + k) * EMB_LD + c] = accs[k];
    }
    __syncthreads();

    // parallel softmax: o16 = tid>>4 owns one o-row; part = tid&15 owns 8 channels
    float* red  = smem + 16 * EMB_LD;        // 256 floats
    float* red2 = red + 256;                 // 256 floats
    const int o16 = tid >> 4;
    const int part = tid & 15;
    const float* srow = sc + o16 * EMB_LD + part * 8;

    float m = -1e30f;
#pragma unroll
    for (int j = 0; j < 8; ++j) m = fmaxf(m, srow[j]);
    red[o16 * 16 + part] = m;
    __syncthreads();
    float M = red[o16 * 16];
#pragma unroll
    for (int p = 1; p < 16; ++p) M = fmaxf(M, red[o16 * 16 + p]);

    float ev[8];
    float s = 0.f;
#pragma unroll
    for (int j = 0; j < 8; ++j) { ev[j] = __expf(srow[j] - M); s += ev[j]; }
    red2[o16 * 16 + part] = s;
    __syncthreads();
    float Sum = 0.f;
#pragma unroll
    for (int p = 0; p < 16; ++p) Sum += red2[o16 * 16 + p];
    float inv = 1.f / Sum;

    float* wrow = w + ((size_t)(b * OO + obase + o16)) * CCH + part * 8;
#pragma unroll
    for (int j = 0; j < 8; ++j) wrow[j] = ev[j] * inv;
}

// ---------------- K2: out[b,t,o] = sum_c eeg[b,t,c] * w[b,o,c] ----------------
// 256 threads = 4 independent waves (no __syncthreads). Each wave owns 64 t-rows,
// lane owns one row, acc[64] IN REGISTERS (all indices compile-time constant —
// the output phase is fully unrolled; runtime-indexing acc[] demotes it to
// scratch and was the R1/R2 17x write-amplification bug).
#define K2_LD 36   // staging row stride (floats); conflict-free for both patterns

__global__ __launch_bounds__(256, 4) void k2_merge(const float* __restrict__ eeg,
                                                   const float* __restrict__ w,
                                                   float* __restrict__ out) {
    __shared__ float lds[4 * 64 * K2_LD];   // 36 KB
    const int b = blockIdx.y;
    const int t0 = blockIdx.x * 256;
    const int lane = threadIdx.x & 63;
    const int wv = __builtin_amdgcn_readfirstlane(threadIdx.x >> 6);
    float* lw = lds + wv * 64 * K2_LD;

    const float* eb = eeg + ((size_t)b * TT + t0 + wv * 64) * CCH;
    const float* wb = w + (size_t)b * OO * CCH;   // uniform -> scalar loads

    float acc[OO];
#pragma unroll
    for (int o = 0; o < OO; ++o) acc[o] = 0.f;

#pragma unroll 1
    for (int ct = 0; ct < CCH; ct += 32) {
        // stage this wave's 64 rows x 32 cols: 8 float4 per lane, coalesced
#pragma unroll
        for (int p = 0; p < 8; ++p) {
            int idx = p * 64 + lane;
            int r = idx >> 3;
            int c4 = idx & 7;
            float4 v = *(const float4*)(eb + r * CCH + ct + c4 * 4);
            *(float4*)(lw + r * K2_LD + c4 * 4) = v;
        }
        __builtin_amdgcn_wave_barrier();
        // accumulate: k in chunks of 8 to bound register pressure
#pragma unroll 1
        for (int k8 = 0; k8 < 4; ++k8) {
            float4 va = *(const float4*)(lw + lane * K2_LD + k8 * 8);
            float4 vb = *(const float4*)(lw + lane * K2_LD + k8 * 8 + 4);
#pragma unroll
            for (int o = 0; o < OO; ++o) {
                const float* wr = wb + o * CCH + ct + k8 * 8;
                float a = acc[o];
                a = fmaf(va.x, wr[0], a);
                a = fmaf(va.y, wr[1], a);
                a = fmaf(va.z, wr[2], a);
                a = fmaf(va.w, wr[3], a);
                a = fmaf(vb.x, wr[4], a);
                a = fmaf(vb.y, wr[5], a);
                a = fmaf(vb.z, wr[6], a);
                a = fmaf(vb.w, wr[7], a);
                acc[o] = a;
            }
        }
        __builtin_amdgcn_wave_barrier();
    }

    // ---- output phase, FULLY UNROLLED (all acc[] indices static) ----
    const size_t orow = (size_t)b * TT + t0 + wv * 64;

    // oh = 0: acc[0..31]
#pragma unroll
    for (int j = 0; j < 32; ++j) lw[lane * 33 + j] = acc[j];
    __builtin_amdgcn_wave_barrier();
#pragma unroll
    for (int p = 0; p < 8; ++p) {
        int idx = p * 64 + lane;
        int r = idx >> 3;
        int f4 = idx & 7;
        float4 v;
        v.x = lw[r * 33 + f4 * 4 + 0];
        v.y = lw[r * 33 + f4 * 4 + 1];
        v.z = lw[r * 33 + f4 * 4 + 2];
        v.w = lw[r * 33 + f4 * 4 + 3];
        *(float4*)(out + (orow + r) * OO + f4 * 4) = v;
    }
    __builtin_amdgcn_wave_barrier();

    // oh = 1: acc[32..63]
#pragma unroll
    for (int j = 0; j < 32; ++j) lw[lane * 33 + j] = acc[32 + j];
    __builtin_amdgcn_wave_barrier();
#pragma unroll
    for (int p = 0; p < 8; ++p) {
        int idx = p * 64 + lane;
        int r = idx >> 3;
        int f4 = idx & 7;
        float4 v;
        v.x = lw[r * 33 + f4 * 4 + 0];
        v.y = lw[r * 33 + f4 * 4 + 1];
        v.z = lw[r * 33 + f4 * 4 + 2];
        v.w = lw[r * 33 + f4 * 4 + 3];
        *(float4*)(out + (orow + r) * OO + 32 + f4 * 4) = v;
    }
}

extern "C" void kernel_launch(void* const* d_in, const int* in_sizes, int n_in,
                              void* d_out, int out_size, void* d_ws, size_t ws_size,
                              hipStream_t stream) {
    const float* eeg   = (const float*)d_in[0];   // [B,T,C]
    const float* pos   = (const float*)d_in[1];   // [B,C,2]
    const float* heads = (const float*)d_in[2];   // [O,D]
    float* out = (float*)d_out;                   // [B,T,O]

    float* ws_f = (float*)d_ws;
    float* Ht = ws_f;                 // 288*64 = 18432 floats
    float* w  = ws_f + DD * OO;       // 32*64*128 = 262144 floats

    k0_transpose_heads<<<(OO * DD + 255) / 256, 256, 0, stream>>>(heads, Ht);
    k1_weights<<<dim3(BB, 4), 256, 0, stream>>>(pos, Ht, w);
    k2_merge<<<dim3(TT / 256, BB), 256, 0, stream>>>(eeg, w, out);
}

// Round 4
// 72.613 us; speedup vs baseline: 5.3452x; 2.2217x over previous
//
#include <hip/hip_runtime.h>
#include <math.h>

#define BB 32
#define TT 8192
#define CCH 128
#define OO 64
#define DD 288
#define NFREQ 12
#define NIJ 144

typedef short bf16x8 __attribute__((ext_vector_type(8)));
typedef float f32x4 __attribute__((ext_vector_type(4)));

__device__ __forceinline__ unsigned short rne_bf16(float x) {
    unsigned u = __float_as_uint(x);
    u += 0x7fffu + ((u >> 16) & 1u);
    return (unsigned short)(u >> 16);
}

// ---------------- K0: transpose heads [64][288] -> Ht [288][64] ----------------
__global__ __launch_bounds__(256) void k0_transpose_heads(const float* __restrict__ heads,
                                                          float* __restrict__ Ht) {
    int idx = blockIdx.x * 256 + threadIdx.x;
    if (idx < OO * DD) {
        int o = idx / DD;
        int d = idx - o * DD;
        Ht[d * OO + o] = heads[idx];
    }
}

// ---------------- K1: fourier emb + scores + softmax -> w [B][O][C] ----------------
#define IJ_CHUNK 36
#define EMB_LD 129

__global__ __launch_bounds__(256) void k1_weights(const float* __restrict__ pos,
                                                  const float* __restrict__ Ht,
                                                  float* __restrict__ w) {
    __shared__ float smem[2 * IJ_CHUNK * EMB_LD];   // 9288 floats = 37 KB
    float* cos_s = smem;
    float* sin_s = smem + IJ_CHUNK * EMB_LD;

    const int b = blockIdx.x;
    const int obase = blockIdx.y * 16;
    const int tid = threadIdx.x;
    const int c = tid & 127;
    const int hh = __builtin_amdgcn_readfirstlane(tid >> 7);  // wave-uniform

    const float* posb = pos + b * CCH * 2;
    const float S = 4.487989505128276f;  // 2*pi/1.4

    float accs[8];
#pragma unroll
    for (int k = 0; k < 8; ++k) accs[k] = 0.f;

#pragma unroll 1
    for (int cc = 0; cc < NIJ; cc += IJ_CHUNK) {
#pragma unroll 1
        for (int it = 0; it < (IJ_CHUNK * CCH) / 256; ++it) {
            int idx = it * 256 + tid;
            int ec = idx & 127;
            int ijl = idx >> 7;
            int ij = cc + ijl;
            int i = ij / NFREQ;
            int j = ij - i * NFREQ;
            float px = posb[2 * ec] + 0.2f;
            float py = posb[2 * ec + 1] + 0.2f;
            float ang = px * (S * (float)i) + py * (S * (float)j);
            float sv, cv;
            __sincosf(ang, &sv, &cv);
            cos_s[ijl * EMB_LD + ec] = cv;
            sin_s[ijl * EMB_LD + ec] = sv;
        }
        __syncthreads();
#pragma unroll 4
        for (int ijl = 0; ijl < IJ_CHUNK; ++ijl) {
            float cv = cos_s[ijl * EMB_LD + c];
            float sv = sin_s[ijl * EMB_LD + c];
            const float* hc = Ht + (cc + ijl) * OO + obase + hh * 8;
            const float* hs = Ht + (NIJ + cc + ijl) * OO + obase + hh * 8;
#pragma unroll
            for (int k = 0; k < 8; ++k) {
                accs[k] = fmaf(cv, hc[k], fmaf(sv, hs[k], accs[k]));
            }
        }
        __syncthreads();
    }

    // scores -> LDS [16][129]
    float* sc = smem;
#pragma unroll
    for (int k = 0; k < 8; ++k) {
        sc[(hh * 8 + k) * EMB_LD + c] = accs[k];
    }
    __syncthreads();

    // parallel softmax: o16 = tid>>4 owns one o-row; part = tid&15 owns 8 channels
    float* red  = smem + 16 * EMB_LD;        // 256 floats
    float* red2 = red + 256;                 // 256 floats
    const int o16 = tid >> 4;
    const int part = tid & 15;
    const float* srow = sc + o16 * EMB_LD + part * 8;

    float m = -1e30f;
#pragma unroll
    for (int j = 0; j < 8; ++j) m = fmaxf(m, srow[j]);
    red[o16 * 16 + part] = m;
    __syncthreads();
    float M = red[o16 * 16];
#pragma unroll
    for (int p = 1; p < 16; ++p) M = fmaxf(M, red[o16 * 16 + p]);

    float ev[8];
    float s = 0.f;
#pragma unroll
    for (int j = 0; j < 8; ++j) { ev[j] = __expf(srow[j] - M); s += ev[j]; }
    red2[o16 * 16 + part] = s;
    __syncthreads();
    float Sum = 0.f;
#pragma unroll
    for (int p = 0; p < 16; ++p) Sum += red2[o16 * 16 + p];
    float inv = 1.f / Sum;

    float* wrow = w + ((size_t)(b * OO + obase + o16)) * CCH + part * 8;
#pragma unroll
    for (int j = 0; j < 8; ++j) wrow[j] = ev[j] * inv;
}

// ---------------- K1b: pack weights into MFMA B-fragments (split bf16) ----------------
// B operand of mfma_f32_16x16x32_bf16: lane holds B[k][col], col = lane&15,
// k = (lane>>4)*8 + i (i=0..7). Per (b, kc=c/32, ot=o/16): 64 lanes x 8 bf16 = uint4/lane.
// frag index: (((b*4 + kc)*4 + ot)*64 + lane)
__global__ __launch_bounds__(256) void k1b_frag(const float* __restrict__ w,
                                                uint4* __restrict__ fragHi,
                                                uint4* __restrict__ fragLo) {
    const int b = blockIdx.x;
    const int kc = blockIdx.y;
    const int ot = threadIdx.x >> 6;
    const int lane = threadIdx.x & 63;
    const int o = ot * 16 + (lane & 15);
    const int cbase = kc * 32 + (lane >> 4) * 8;
    const float* wrow = w + ((size_t)(b * OO + o)) * CCH + cbase;

    unsigned short hi[8], lo[8];
#pragma unroll
    for (int i = 0; i < 8; ++i) {
        float x = wrow[i];
        unsigned short h = rne_bf16(x);
        float hf = __uint_as_float((unsigned)h << 16);
        hi[i] = h;
        lo[i] = rne_bf16(x - hf);
    }
    uint4 vh, vl;
    vh.x = (unsigned)hi[0] | ((unsigned)hi[1] << 16);
    vh.y = (unsigned)hi[2] | ((unsigned)hi[3] << 16);
    vh.z = (unsigned)hi[4] | ((unsigned)hi[5] << 16);
    vh.w = (unsigned)hi[6] | ((unsigned)hi[7] << 16);
    vl.x = (unsigned)lo[0] | ((unsigned)lo[1] << 16);
    vl.y = (unsigned)lo[2] | ((unsigned)lo[3] << 16);
    vl.z = (unsigned)lo[4] | ((unsigned)lo[5] << 16);
    vl.w = (unsigned)lo[6] | ((unsigned)lo[7] << 16);
    const int idx = ((b * 4 + kc) * 4 + ot) * 64 + lane;
    fragHi[idx] = vh;
    fragLo[idx] = vl;
}

// ---------------- K2: out[b,t,o] = sum_c eeg[b,t,c] * w[b,o,c] via split-bf16 MFMA ----
// Block: 256 thr = 4 waves, each wave owns 64 t-rows (4 tiles of 16).
// A: lane holds eeg[row = lane&15][k = (lane>>4)*8 + i], split hi/lo bf16 on the fly.
// B: preformed fragments (k1b), same per-lane k-indexing => any internal k-permutation
//    cancels between A and B. C/D: col = lane&15, row = (lane>>4)*4 + reg (HW-verified).
// 3 MFMA per (tile): aHi*bHi + aHi*bLo + aLo*bHi  (fp32-level accuracy).
__global__ __launch_bounds__(256) void k2_mfma(const float* __restrict__ eeg,
                                               const uint4* __restrict__ fragHi,
                                               const uint4* __restrict__ fragLo,
                                               float* __restrict__ out) {
    const int b = blockIdx.y;
    const int t0 = blockIdx.x * 256;
    const int lane = threadIdx.x & 63;
    const int wv = __builtin_amdgcn_readfirstlane(threadIdx.x >> 6);
    const int r16 = lane & 15;
    const int kq = lane >> 4;

    const float* ebase = eeg + ((size_t)b * TT + t0 + wv * 64) * CCH;

    f32x4 acc[4][4];
#pragma unroll
    for (int tt = 0; tt < 4; ++tt)
#pragma unroll
        for (int ot = 0; ot < 4; ++ot)
            acc[tt][ot] = (f32x4){0.f, 0.f, 0.f, 0.f};

    union U { uint4 u; bf16x8 v; };

#pragma unroll 1
    for (int kc = 0; kc < 4; ++kc) {
        const uint4* fh = fragHi + (size_t)((b * 4 + kc) * 4) * 64 + lane;
        const uint4* fl = fragLo + (size_t)((b * 4 + kc) * 4) * 64 + lane;
        bf16x8 bh[4], bl[4];
#pragma unroll
        for (int ot = 0; ot < 4; ++ot) {
            U uh, ul;
            uh.u = fh[ot * 64];
            ul.u = fl[ot * 64];
            bh[ot] = uh.v;
            bl[ot] = ul.v;
        }
#pragma unroll
        for (int tt = 0; tt < 4; ++tt) {
            const float* ap = ebase + (size_t)(tt * 16 + r16) * CCH + kc * 32 + kq * 8;
            float4 v0 = *(const float4*)ap;
            float4 v1 = *(const float4*)(ap + 4);
            float xs[8] = {v0.x, v0.y, v0.z, v0.w, v1.x, v1.y, v1.z, v1.w};
            bf16x8 ah, al;
#pragma unroll
            for (int i = 0; i < 8; ++i) {
                float x = xs[i];
                unsigned short h = rne_bf16(x);
                ah[i] = (short)h;
                float hf = __uint_as_float((unsigned)h << 16);
                al[i] = (short)rne_bf16(x - hf);
            }
#pragma unroll
            for (int ot = 0; ot < 4; ++ot) {
                acc[tt][ot] = __builtin_amdgcn_mfma_f32_16x16x32_bf16(ah, bh[ot], acc[tt][ot], 0, 0, 0);
                acc[tt][ot] = __builtin_amdgcn_mfma_f32_16x16x32_bf16(ah, bl[ot], acc[tt][ot], 0, 0, 0);
                acc[tt][ot] = __builtin_amdgcn_mfma_f32_16x16x32_bf16(al, bh[ot], acc[tt][ot], 0, 0, 0);
            }
        }
    }

    // epilogue: lane holds D[row = kq*4 + reg][col = r16] per tile
    const size_t orow0 = (size_t)b * TT + t0 + wv * 64;
#pragma unroll
    for (int tt = 0; tt < 4; ++tt) {
#pragma unroll
        for (int reg = 0; reg < 4; ++reg) {
            const size_t row = orow0 + tt * 16 + kq * 4 + reg;
#pragma unroll
            for (int ot = 0; ot < 4; ++ot) {
                out[row * OO + ot * 16 + r16] = acc[tt][ot][reg];
            }
        }
    }
}

extern "C" void kernel_launch(void* const* d_in, const int* in_sizes, int n_in,
                              void* d_out, int out_size, void* d_ws, size_t ws_size,
                              hipStream_t stream) {
    const float* eeg   = (const float*)d_in[0];   // [B,T,C]
    const float* pos   = (const float*)d_in[1];   // [B,C,2]
    const float* heads = (const float*)d_in[2];   // [O,D]
    float* out = (float*)d_out;                   // [B,T,O]

    char* ws = (char*)d_ws;
    float* Ht      = (float*)ws;                          // 288*64*4   = 73728 B
    float* w       = (float*)(ws + 73728);                // 32*64*128*4 = 1048576 B
    uint4* fragHi  = (uint4*)(ws + 73728 + 1048576);      // 32*4*4*64*16 = 524288 B
    uint4* fragLo  = (uint4*)(ws + 73728 + 1048576 + 524288);

    k0_transpose_heads<<<(OO * DD + 255) / 256, 256, 0, stream>>>(heads, Ht);
    k1_weights<<<dim3(BB, 4), 256, 0, stream>>>(pos, Ht, w);
    k1b_frag<<<dim3(BB, 4), 256, 0, stream>>>(w, fragHi, fragLo);
    k2_mfma<<<dim3(TT / 256, BB), 256, 0, stream>>>(eeg, fragHi, fragLo, out);
}